// Round 1
// baseline (5208.409 us; speedup 1.0000x reference)
//
#include <hip/hip_runtime.h>

#define NUSER 100000
#define NITEM 150000
#define NBRAND 5000
#define NNODES (NUSER + NITEM + NBRAND)   // 255000
#define DIM 64
#define NOUTROWS (NUSER + NITEM)          // 250000

// ---------------------------------------------------------------------------
// init: x = concat(user, item, brand); acc = x   (float4 over NNODES*16)
// ---------------------------------------------------------------------------
__global__ void lgcn_init(const float4* __restrict__ u,
                          const float4* __restrict__ it,
                          const float4* __restrict__ br,
                          float4* __restrict__ x,
                          float4* __restrict__ acc) {
    int i = blockIdx.x * blockDim.x + threadIdx.x;
    const int total = NNODES * (DIM / 4);
    if (i >= total) return;
    float4 v;
    if (i < NUSER * (DIM / 4)) {
        v = u[i];
    } else if (i < (NUSER + NITEM) * (DIM / 4)) {
        v = it[i - NUSER * (DIM / 4)];
    } else {
        v = br[i - (NUSER + NITEM) * (DIM / 4)];
    }
    x[i] = v;
    acc[i] = v;
}

// ---------------------------------------------------------------------------
// spmm: y[row] += val * x[col]   (COO, 16 lanes per edge, float4 per lane)
// ---------------------------------------------------------------------------
__global__ void lgcn_spmm(const int* __restrict__ rows,
                          const int* __restrict__ cols,
                          const float* __restrict__ vals,
                          const float* __restrict__ x,
                          float* __restrict__ y,
                          int nedges) {
    int t = blockIdx.x * blockDim.x + threadIdx.x;
    int e = t >> 4;        // 16 lanes per edge
    int l = t & 15;
    if (e >= nedges) return;
    int r = rows[e];
    int c = cols[e];
    float v = vals[e];
    float4 xv = *reinterpret_cast<const float4*>(x + (size_t)c * DIM + l * 4);
    float* yp = y + (size_t)r * DIM + l * 4;
    unsafeAtomicAdd(yp + 0, v * xv.x);
    unsafeAtomicAdd(yp + 1, v * xv.y);
    unsafeAtomicAdd(yp + 2, v * xv.z);
    unsafeAtomicAdd(yp + 3, v * xv.w);
}

// ---------------------------------------------------------------------------
// acc += y   (float4)
// ---------------------------------------------------------------------------
__global__ void lgcn_accadd(float4* __restrict__ acc,
                            const float4* __restrict__ y) {
    int i = blockIdx.x * blockDim.x + threadIdx.x;
    const int total = NNODES * (DIM / 4);
    if (i >= total) return;
    float4 a = acc[i];
    float4 b = y[i];
    a.x += b.x; a.y += b.y; a.z += b.z; a.w += b.w;
    acc[i] = a;
}

// ---------------------------------------------------------------------------
// out = acc[0:250000 rows] * 0.25
// ---------------------------------------------------------------------------
__global__ void lgcn_final(const float4* __restrict__ acc,
                           float4* __restrict__ out) {
    int i = blockIdx.x * blockDim.x + threadIdx.x;
    const int total = NOUTROWS * (DIM / 4);
    if (i >= total) return;
    float4 a = acc[i];
    a.x *= 0.25f; a.y *= 0.25f; a.z *= 0.25f; a.w *= 0.25f;
    out[i] = a;
}

extern "C" void kernel_launch(void* const* d_in, const int* in_sizes, int n_in,
                              void* d_out, int out_size, void* d_ws, size_t ws_size,
                              hipStream_t stream) {
    const float4* u  = (const float4*)d_in[0];
    const float4* it = (const float4*)d_in[1];
    const float4* br = (const float4*)d_in[2];
    const int*   rows = (const int*)d_in[3];
    const int*   cols = (const int*)d_in[4];
    const float* vals = (const float*)d_in[5];
    const int nedges = in_sizes[3];
    float* out = (float*)d_out;

    const size_t nodeElems = (size_t)NNODES * DIM;   // floats per buffer
    float* x   = (float*)d_ws;
    float* y   = x + nodeElems;
    float* acc = y + nodeElems;

    const int THREADS = 256;
    const int totalVec = NNODES * (DIM / 4);
    const int initBlocks = (totalVec + THREADS - 1) / THREADS;

    lgcn_init<<<initBlocks, THREADS, 0, stream>>>(u, it, br, (float4*)x, (float4*)acc);

    const int spmmThreadsTotal = nedges * 16;
    const int spmmBlocks = (spmmThreadsTotal + THREADS - 1) / THREADS;

    for (int layer = 0; layer < 3; ++layer) {
        hipMemsetAsync(y, 0, nodeElems * sizeof(float), stream);
        lgcn_spmm<<<spmmBlocks, THREADS, 0, stream>>>(rows, cols, vals, x, y, nedges);
        lgcn_accadd<<<initBlocks, THREADS, 0, stream>>>((float4*)acc, (const float4*)y);
        float* tmp = x; x = y; y = tmp;   // next layer's input is this layer's output
    }

    const int outVec = NOUTROWS * (DIM / 4);
    const int outBlocks = (outVec + THREADS - 1) / THREADS;
    lgcn_final<<<outBlocks, THREADS, 0, stream>>>((const float4*)acc, (float4*)out);
}

// Round 2
// 531.114 us; speedup vs baseline: 9.8066x; 9.8066x over previous
//
#include <hip/hip_runtime.h>

#define NUSER 100000
#define NITEM 150000
#define NBRAND 5000
#define NNODES (NUSER + NITEM + NBRAND)   // 255000
#define DIM 64
#define NOUTROWS (NUSER + NITEM)          // 250000

// ============================ CSR build =====================================

__global__ void lgcn_hist(const int* __restrict__ rows, int* __restrict__ counts, int nedges) {
    int e = blockIdx.x * blockDim.x + threadIdx.x;
    if (e >= nedges) return;
    atomicAdd(&counts[rows[e]], 1);
}

// scan1: per-block (2048 elems) exclusive scan; block totals to blksum
__global__ void lgcn_scan1(const int* __restrict__ counts, int* __restrict__ row_ptr,
                           int* __restrict__ blksum) {
    __shared__ int lds[256];
    int base = blockIdx.x * 2048 + threadIdx.x * 8;
    int pre[8];
    int s = 0;
    #pragma unroll
    for (int k = 0; k < 8; ++k) {
        int idx = base + k;
        int c = (idx < NNODES) ? counts[idx] : 0;
        pre[k] = s;
        s += c;
    }
    lds[threadIdx.x] = s;
    __syncthreads();
    for (int off = 1; off < 256; off <<= 1) {
        int t = (threadIdx.x >= off) ? lds[threadIdx.x - off] : 0;
        __syncthreads();
        lds[threadIdx.x] += t;
        __syncthreads();
    }
    int excl = lds[threadIdx.x] - s;
    if (threadIdx.x == 255) blksum[blockIdx.x] = lds[255];
    #pragma unroll
    for (int k = 0; k < 8; ++k) {
        int idx = base + k;
        if (idx < NNODES) row_ptr[idx] = pre[k] + excl;
    }
}

// scan2: single block, exclusive scan of block sums; writes row_ptr[NNODES]=total
__global__ void lgcn_scan2(int* __restrict__ blksum, int nblk,
                           int* __restrict__ row_ptr, int total) {
    __shared__ int lds[256];
    int v = (threadIdx.x < nblk) ? blksum[threadIdx.x] : 0;
    lds[threadIdx.x] = v;
    __syncthreads();
    for (int off = 1; off < 256; off <<= 1) {
        int t = (threadIdx.x >= off) ? lds[threadIdx.x - off] : 0;
        __syncthreads();
        lds[threadIdx.x] += t;
        __syncthreads();
    }
    int excl = lds[threadIdx.x] - v;
    if (threadIdx.x < nblk) blksum[threadIdx.x] = excl;
    if (threadIdx.x == 0) row_ptr[NNODES] = total;
}

// scan3: add block offsets
__global__ void lgcn_scan3(int* __restrict__ row_ptr, const int* __restrict__ blksum) {
    int idx = blockIdx.x * blockDim.x + threadIdx.x;
    if (idx < NNODES) row_ptr[idx] += blksum[idx >> 11];
}

// scatter edges into row-sorted order, packing (col, val) into 8 bytes
__global__ void lgcn_scatter(const int* __restrict__ rows, const int* __restrict__ cols,
                             const float* __restrict__ vals, int* __restrict__ cursor,
                             int2* __restrict__ colval, int nedges) {
    int e = blockIdx.x * blockDim.x + threadIdx.x;
    if (e >= nedges) return;
    int r = rows[e];
    int pos = atomicAdd(&cursor[r], 1);
    int2 cv;
    cv.x = cols[e];
    cv.y = __float_as_int(vals[e]);
    colval[pos] = cv;
}

// ============================ init / spmm ===================================

// x = concat(u,it,br); acc_main(d_out rows<250K) = x; acc_brand = brand part
__global__ void lgcn_init(const float4* __restrict__ u,
                          const float4* __restrict__ it,
                          const float4* __restrict__ br,
                          float4* __restrict__ x,
                          float4* __restrict__ accm,
                          float4* __restrict__ accb) {
    int i = blockIdx.x * blockDim.x + threadIdx.x;
    const int total = NNODES * (DIM / 4);
    if (i >= total) return;
    float4 v;
    if (i < NUSER * (DIM / 4)) {
        v = u[i];
    } else if (i < (NUSER + NITEM) * (DIM / 4)) {
        v = it[i - NUSER * (DIM / 4)];
    } else {
        v = br[i - (NUSER + NITEM) * (DIM / 4)];
    }
    x[i] = v;
    if (i < NOUTROWS * (DIM / 4)) accm[i] = v;
    else                          accb[i - NOUTROWS * (DIM / 4)] = v;
}

// CSR SpMM: 16 lanes per row; fused acc update. FINAL fuses *0.25 into d_out
// and skips brand rows + y write.
template <bool WRITE_Y, bool FINAL>
__global__ void lgcn_spmm_csr(const int* __restrict__ row_ptr,
                              const int2* __restrict__ colval,
                              const float* __restrict__ x,
                              float* __restrict__ y,
                              float* __restrict__ accm,
                              float* __restrict__ accb) {
    int t = blockIdx.x * blockDim.x + threadIdx.x;
    int row = t >> 4;
    int l = t & 15;
    if (row >= NNODES) return;
    if (FINAL && row >= NOUTROWS) return;   // brand result unused in last layer
    int beg = row_ptr[row];
    int end = row_ptr[row + 1];
    float4 s = make_float4(0.f, 0.f, 0.f, 0.f);
    for (int p = beg; p < end; ++p) {
        int2 cv = colval[p];
        float v = __int_as_float(cv.y);
        float4 xv = *reinterpret_cast<const float4*>(x + (size_t)cv.x * DIM + l * 4);
        s.x += v * xv.x;
        s.y += v * xv.y;
        s.z += v * xv.z;
        s.w += v * xv.w;
    }
    size_t off = (size_t)row * DIM + l * 4;
    if (WRITE_Y) *reinterpret_cast<float4*>(y + off) = s;
    if (!FINAL) {
        float4* ap = (row < NOUTROWS)
                         ? reinterpret_cast<float4*>(accm + off)
                         : reinterpret_cast<float4*>(accb + off - (size_t)NOUTROWS * DIM);
        float4 a = *ap;
        a.x += s.x; a.y += s.y; a.z += s.z; a.w += s.w;
        *ap = a;
    } else {
        float4* ap = reinterpret_cast<float4*>(accm + off);
        float4 a = *ap;
        a.x = (a.x + s.x) * 0.25f;
        a.y = (a.y + s.y) * 0.25f;
        a.z = (a.z + s.z) * 0.25f;
        a.w = (a.w + s.w) * 0.25f;
        *ap = a;
    }
}

// ============================ launch ========================================

static inline size_t align256(size_t x) { return (x + 255) & ~(size_t)255; }

extern "C" void kernel_launch(void* const* d_in, const int* in_sizes, int n_in,
                              void* d_out, int out_size, void* d_ws, size_t ws_size,
                              hipStream_t stream) {
    const float4* u  = (const float4*)d_in[0];
    const float4* it = (const float4*)d_in[1];
    const float4* br = (const float4*)d_in[2];
    const int*   rows = (const int*)d_in[3];
    const int*   cols = (const int*)d_in[4];
    const float* vals = (const float*)d_in[5];
    const int nedges = in_sizes[3];
    float* accm = (float*)d_out;   // acc for user+item rows lives in d_out

    // workspace layout
    char* ws = (char*)d_ws;
    size_t o = 0;
    float* x      = (float*)(ws + o); o = align256(o + (size_t)NNODES * DIM * 4);
    float* y      = (float*)(ws + o); o = align256(o + (size_t)NNODES * DIM * 4);
    float* accb   = (float*)(ws + o); o = align256(o + (size_t)NBRAND * DIM * 4);
    int*   counts = (int*)(ws + o);   o = align256(o + (size_t)NNODES * 4);
    int*   rowptr = (int*)(ws + o);   o = align256(o + (size_t)(NNODES + 1) * 4);
    int*   cursor = (int*)(ws + o);   o = align256(o + (size_t)NNODES * 4);
    int*   blksum = (int*)(ws + o);   o = align256(o + 256 * 4);
    int2*  colval = (int2*)(ws + o);  o = align256(o + (size_t)nedges * 8);

    const int THREADS = 256;
    const int NBLK_SCAN = (NNODES + 2047) / 2048;          // 125
    const int edgeBlocks = (nedges + THREADS - 1) / THREADS;
    const int nodeBlocks = (NNODES + THREADS - 1) / THREADS;
    const int vecTotal = NNODES * (DIM / 4);
    const int vecBlocks = (vecTotal + THREADS - 1) / THREADS;
    const int spmmBlocks = (NNODES * 16 + THREADS - 1) / THREADS;

    // --- CSR build ---
    hipMemsetAsync(counts, 0, (size_t)NNODES * 4, stream);
    lgcn_hist<<<edgeBlocks, THREADS, 0, stream>>>(rows, counts, nedges);
    lgcn_scan1<<<NBLK_SCAN, THREADS, 0, stream>>>(counts, rowptr, blksum);
    lgcn_scan2<<<1, THREADS, 0, stream>>>(blksum, NBLK_SCAN, rowptr, nedges);
    lgcn_scan3<<<nodeBlocks, THREADS, 0, stream>>>(rowptr, blksum);
    hipMemcpyAsync(cursor, rowptr, (size_t)NNODES * 4, hipMemcpyDeviceToDevice, stream);
    lgcn_scatter<<<edgeBlocks, THREADS, 0, stream>>>(rows, cols, vals, cursor, colval, nedges);

    // --- init embeddings + accumulators ---
    lgcn_init<<<vecBlocks, THREADS, 0, stream>>>(u, it, br, (float4*)x, (float4*)accm, (float4*)accb);

    // --- 3 propagation layers (ping-pong x<->y, acc fused) ---
    lgcn_spmm_csr<true,  false><<<spmmBlocks, THREADS, 0, stream>>>(rowptr, colval, x, y, accm, accb);
    lgcn_spmm_csr<true,  false><<<spmmBlocks, THREADS, 0, stream>>>(rowptr, colval, y, x, accm, accb);
    lgcn_spmm_csr<false, true ><<<spmmBlocks, THREADS, 0, stream>>>(rowptr, colval, x, nullptr, accm, accb);
}